// Round 3
// baseline (2280.490 us; speedup 1.0000x reference)
//
#include <hip/hip_runtime.h>

#define EDIM 256
#define NROW 16384
#define NCODE 16384
#define SPLIT 4
#define KC 16

using f32x16 = __attribute__((ext_vector_type(16))) float;

// ||e_j||^2 in double, rounded once to f32
__global__ __launch_bounds__(256) void k_es(const float* __restrict__ e,
                                            float* __restrict__ es) {
  const int row = blockIdx.x * 4 + (threadIdx.x >> 6);
  const int lane = threadIdx.x & 63;
  float4 v = *(const float4*)&e[row * EDIM + lane * 4];
  double s = (double)v.x * v.x + (double)v.y * v.y + (double)v.z * v.z + (double)v.w * v.w;
#pragma unroll
  for (int off = 32; off > 0; off >>= 1) s += __shfl_down(s, off, 64);
  if (lane == 0) es[row] = (float)s;
}

__global__ __launch_bounds__(256) void k_init(unsigned long long* __restrict__ packed) {
  packed[blockIdx.x * 256 + threadIdx.x] = ~0ull;
}

__global__ __launch_bounds__(256) void k_unpack(const unsigned long long* __restrict__ packed,
                                                int* __restrict__ out) {
  const int n = blockIdx.x * 256 + threadIdx.x;
  out[n] = (int)(unsigned)(packed[n] & 0xffffffffull);
}

// order-monotone map of float bits
__device__ __forceinline__ unsigned fmono(float f) {
  unsigned u = __float_as_uint(f);
  return u ^ ((u & 0x80000000u) ? 0xffffffffu : 0x80000000u);
}

// Main: block = 64 rows x 4096 codes (SPLIT=4). Wave wv owns rows wv*16..+15.
// A operand: wave-uniform f32x16 load straight from z (k-major) -> scalar path,
// zero LDS traffic. B: [k][n] in LDS, one ds_read_b128 per k per lane (4 codes).
// LDS demand/CU/k-step = 16w*12cyc = 192 << VALU 512 -> VALU-bound by design.
__global__ __launch_bounds__(256, 2) void k_main(const float* __restrict__ z,
                                                 const float* __restrict__ e,
                                                 const float* __restrict__ es,
                                                 unsigned long long* __restrict__ packed) {
  extern __shared__ char smem[];
  float* Bs = (float*)smem;                     // [2][16][256] 32KB
  double* zred = (double*)(smem + 16384);       // overlays Bs buf1 (dead until step0's writeB)
  float* zsf = (float*)(smem + 32768);          // 1KB, persistent

  const int tid = threadIdx.x;
  const int lane = tid & 63;
  const int wvu = __builtin_amdgcn_readfirstlane(tid >> 6);
  const int n0 = lane * 4;  // this lane's 4 codes within the 256-code tile

  // XCD swizzle: bid&7 ~ XCD; 2 XCDs per split -> 4MB B-panel per XCD-pair L2
  const int bid = (int)blockIdx.x;
  const int sp = (bid & 7) >> 1;
  const int rt = ((bid >> 3) << 1) | (bid & 1);
  const int bb = rt >> 4;
  const int hw0 = (rt & 15) << 6;
  const float* zb = z + bb * (EDIM * 1024) + hw0;  // + k*1024 + m
  const float* zA = zb + wvu * 16;                 // wave's 16 rows; A(k,i)=zA[k*1024+i]

  const int codeBase = sp * (NCODE / SPLIT);
  const int NSTEP = (NCODE / SPLIT) / 256 * (EDIM / KC);  // 16 tiles * 16 kc = 256

  float4 bpre[4];
  auto loadB = [&](int gts) {  // thread owns code (ct*256+tid), reads its 16-k slice
    const int ct = gts >> 4, k0 = (gts & 15) * KC;
    const float* g = e + (size_t)(codeBase + ct * 256 + tid) * 256 + k0;
#pragma unroll
    for (int s = 0; s < 4; ++s) bpre[s] = *(const float4*)(g + s * 4);
  };
  auto writeB = [&](int buf) {  // transpose to [k][n]; banks = tid%32 -> 2-way (free)
    float* bw_ = Bs + buf * 4096 + tid;
#pragma unroll
    for (int s = 0; s < 4; ++s) {
      bw_[(4 * s + 0) * 256] = bpre[s].x;
      bw_[(4 * s + 1) * 256] = bpre[s].y;
      bw_[(4 * s + 2) * 256] = bpre[s].z;
      bw_[(4 * s + 3) * 256] = bpre[s].w;
    }
  };

  // ---- prologue: B tile 0 + ||z||^2 (identical numerics to passing rounds)
  loadB(0);
  {
    const int m = tid & 63, qt = tid >> 6;
    const float* zp = zb + (size_t)(qt * 64) * 1024 + m;
    double s = 0.0;
    for (int k = 0; k < 64; ++k) {
      float v = zp[(size_t)k * 1024];
      s = fma((double)v, (double)v, s);
    }
    zred[qt * 64 + m] = s;
  }
  writeB(0);
  __syncthreads();
  if (tid < 64) {
    double sz = (zred[tid] + zred[64 + tid]) + (zred[128 + tid] + zred[192 + tid]);
    zsf[tid] = (float)sz;  // single rounding to f32
  }
  __syncthreads();
  float zsr[16];  // wave-uniform -> SGPRs via readfirstlane
#pragma unroll
  for (int i = 0; i < 16; ++i)
    zsr[i] = __int_as_float(__builtin_amdgcn_readfirstlane(__float_as_int(zsf[wvu * 16 + i])));

  float bestv[16];
  int besti[16];
#pragma unroll
  for (int i = 0; i < 16; ++i) {
    bestv[i] = 3.402823466e+38f;
    besti[i] = 0;
  }

  float acc[16][4];
  int cur = 0;
#pragma unroll 1
  for (int step = 0; step < NSTEP; ++step) {
    const int kc = step & 15, ct = step >> 4;
    if (step + 1 < NSTEP) loadB(step + 1);  // global gathers land during compute
    if (kc == 0) {
#pragma unroll
      for (int i = 0; i < 16; ++i)
#pragma unroll
        for (int j = 0; j < 4; ++j) acc[i][j] = 0.0f;
    }
    const float* bk = Bs + cur * 4096 + n0;
    const float* aK = zA + (size_t)(kc * KC) * 1024;
#pragma unroll 4
    for (int kk = 0; kk < KC; ++kk) {  // strictly ascending k: deterministic fp32 chain
      f32x16 av = *(const f32x16*)(aK + (size_t)kk * 1024);  // wave-uniform -> s_load
      float4 bv = *(const float4*)(bk + kk * 256);           // one ds_read_b128
#pragma unroll
      for (int i = 0; i < 16; ++i) {
        acc[i][0] = fmaf(av[i], bv.x, acc[i][0]);
        acc[i][1] = fmaf(av[i], bv.y, acc[i][1]);
        acc[i][2] = fmaf(av[i], bv.z, acc[i][2]);
        acc[i][3] = fmaf(av[i], bv.w, acc[i][3]);
      }
    }
    if (step + 1 < NSTEP) writeB(cur ^ 1);
    if (kc == 15) {
      // faithful fp32 semantics: d = fl(fl(zs+es) - 2*g); 2*g exact, single rounding
      const int cb = codeBase + ct * 256 + n0;
      float4 ej = *(const float4*)&es[cb];
      float ejv[4] = {ej.x, ej.y, ej.z, ej.w};
#pragma unroll
      for (int i = 0; i < 16; ++i) {
#pragma unroll
        for (int j = 0; j < 4; ++j) {
          float d = (zsr[i] + ejv[j]) - 2.0f * acc[i][j];
          if (d < bestv[i]) {  // strict <: ascending code order -> lowest index wins
            bestv[i] = d;
            besti[i] = cb + j;
          }
        }
      }
    }
    __syncthreads();
    cur ^= 1;
  }

  // ---- cross-lane butterfly per row (wave owns its 16 rows exclusively)
#pragma unroll 1
  for (int i = 0; i < 16; ++i) {
    float v = bestv[i];
    int ix = besti[i];
#pragma unroll
    for (int off = 32; off > 0; off >>= 1) {
      float ov = __shfl_xor(v, off, 64);
      int oi = __shfl_xor(ix, off, 64);
      if (ov < v || (ov == v && oi < ix)) {
        v = ov;
        ix = oi;
      }
    }
    if (lane == 0) {
      unsigned long long key = ((unsigned long long)fmono(v) << 32) | (unsigned)ix;
      atomicMin(&packed[rt * 64 + wvu * 16 + i], key);
    }
  }
}

extern "C" void kernel_launch(void* const* d_in, const int* in_sizes, int n_in,
                              void* d_out, int out_size, void* d_ws, size_t ws_size,
                              hipStream_t stream) {
  const float* z = (const float*)d_in[0];
  const float* e = (const float*)d_in[1];
  int* out = (int*)d_out;

  float* es = (float*)d_ws;                                                 // 64KB
  unsigned long long* packed = (unsigned long long*)((char*)d_ws + 65536);  // 128KB

  k_es<<<dim3(NCODE / 4), dim3(256), 0, stream>>>(e, es);
  k_init<<<dim3(NROW / 256), dim3(256), 0, stream>>>(packed);

  const size_t smem = 32768 + 1024;  // 33KB -> 4 blocks/CU
  hipFuncSetAttribute(reinterpret_cast<const void*>(&k_main),
                      hipFuncAttributeMaxDynamicSharedMemorySize, (int)smem);
  k_main<<<dim3(256 * SPLIT), dim3(256), smem, stream>>>(z, e, es, packed);

  k_unpack<<<dim3(NROW / 256), dim3(256), 0, stream>>>(packed, out);
}

// Round 4
// 694.812 us; speedup vs baseline: 3.2822x; 3.2822x over previous
//
#include <hip/hip_runtime.h>

#define EDIM 256
#define NROW 16384
#define NCODE 16384
#define NBN 128
#define MARGIN 2.0e-4f

typedef _Float16 f16x8 __attribute__((ext_vector_type(8)));
typedef float f32x4 __attribute__((ext_vector_type(4)));

__device__ __forceinline__ void gll16(const void* g, void* l) {
  __builtin_amdgcn_global_load_lds((const __attribute__((address_space(1))) void*)g,
                                   (__attribute__((address_space(3))) void*)l, 16, 0, 0);
}
__device__ __forceinline__ void gll4(const void* g, void* l) {
  __builtin_amdgcn_global_load_lds((const __attribute__((address_space(1))) void*)g,
                                   (__attribute__((address_space(3))) void*)l, 4, 0, 0);
}

// ||e_j||^2 in double, rounded once to f32 (identical to validated rounds)
__global__ __launch_bounds__(256) void k_es(const float* __restrict__ e,
                                            float* __restrict__ es) {
  const int row = blockIdx.x * 4 + (threadIdx.x >> 6);
  const int lane = threadIdx.x & 63;
  float4 v = *(const float4*)&e[row * EDIM + lane * 4];
  double s = (double)v.x * v.x + (double)v.y * v.y + (double)v.z * v.z + (double)v.w * v.w;
#pragma unroll
  for (int off = 32; off > 0; off >>= 1) s += __shfl_down(s, off, 64);
  if (lane == 0) es[row] = (float)s;
}

// e [n][k] f32 -> Eh [n][k] f16, scaled by 2^10 (exact pow2; keeps e' normal in f16)
__global__ __launch_bounds__(256) void k_cvt_e(const float* __restrict__ e,
                                               _Float16* __restrict__ Eh) {
  const int n = blockIdx.x;
  Eh[n * EDIM + threadIdx.x] = (_Float16)(e[n * EDIM + threadIdx.x] * 1024.0f);
}

// z [16][256][32][32] f32 -> Zh [m=16384][k=256] f16 (transpose c<->hw via LDS)
__global__ __launch_bounds__(256) void k_cvt_z(const float* __restrict__ z,
                                               _Float16* __restrict__ Zh) {
  __shared__ float zl[EDIM * 64];  // [c][mloc] 64KB
  const int t = threadIdx.x;
  const int rb = blockIdx.x;  // 256 blocks x 64 rows
  const int bb = rb >> 4;
  const int hw0 = (rb & 15) << 6;
  const float* zbase = z + (size_t)bb * EDIM * 1024 + hw0;
#pragma unroll 4
  for (int rep = 0; rep < 64; ++rep) {
    int c = rep * 4 + (t >> 6);
    zl[c * 64 + (t & 63)] = zbase[(size_t)c * 1024 + (t & 63)];
  }
  __syncthreads();
  const int mloc = t >> 2, part = t & 3;
#pragma unroll
  for (int i = 0; i < 8; ++i) {
    int c0 = part * 64 + i * 8;
    f16x8 v;
#pragma unroll
    for (int j = 0; j < 8; ++j) v[j] = (_Float16)zl[(c0 + j) * 64 + mloc];
    *(f16x8*)&Zh[(size_t)(rb * 64 + mloc) * EDIM + c0] = v;
  }
}

// Phase A: f16 MFMA GEMM h = -2*(z.e). Per (row, 128-code block): local min +
// 128-bit mask of codes within MARGIN of local min. m97-style 128^2 tile, BK=32.
__global__ __launch_bounds__(256, 2) void k_gemm(const _Float16* __restrict__ Zh,
                                                 const _Float16* __restrict__ Eh,
                                                 float* __restrict__ lmin,
                                                 uint4* __restrict__ masks) {
  __shared__ __align__(16) char smem[32768];  // As[2][128][32]f16 | Bs[2][128][32]f16

  const int tid = threadIdx.x;
  const int lane = tid & 63;
  const int wv = tid >> 6;
  const int wm = wv & 1, wn = wv >> 1;
  const int fr = lane & 15;   // frag col-lane
  const int fq = lane >> 4;   // frag row-quad / k-octet

  // bijective XCD swizzle + 16x16 supertiles: XCD x owns bn band [x*16,x*16+16)
  const int bid = (int)blockIdx.x;
  const int wgid = (bid & 7) * 2048 + (bid >> 3);
  const int st = wgid >> 8, wi = wgid & 255;
  const int bm = ((st & 7) << 4) | (wi & 15);
  const int bn = ((st >> 3) << 4) | (wi >> 4);

  const char* zh_b = (const char*)Zh;  // row stride 512B
  const char* eh_b = (const char*)Eh;

  auto stage = [&](int buf, int s) {
#pragma unroll
    for (int i = 0; i < 2; ++i) {
      const int L = (i * 256 + tid) * 16;  // byte in 8KB tile
      const int row = L >> 6, kb = L & 63;
      gll16(zh_b + (size_t)(bm * 128 + row) * 512 + s * 64 + kb,
            smem + buf * 8192 + L);
      gll16(eh_b + (size_t)(bn * 128 + row) * 512 + s * 64 + kb,
            smem + 16384 + buf * 8192 + L);
    }
  };

  f32x4 acc[4][4];
#pragma unroll
  for (int i = 0; i < 4; ++i)
#pragma unroll
    for (int j = 0; j < 4; ++j) acc[i][j] = (f32x4)0.0f;

  stage(0, 0);
  __syncthreads();
#pragma unroll 1
  for (int s = 0; s < 8; ++s) {
    if (s + 1 < 8) stage((s + 1) & 1, s + 1);
    const char* aB = smem + (s & 1) * 8192;
    const char* bB = smem + 16384 + (s & 1) * 8192;
    f16x8 af[4], bf[4];
#pragma unroll
    for (int mi = 0; mi < 4; ++mi)
      af[mi] = *(const f16x8*)(aB + (wm * 64 + mi * 16 + fr) * 64 + fq * 16);
#pragma unroll
    for (int ni = 0; ni < 4; ++ni)
      bf[ni] = *(const f16x8*)(bB + (wn * 64 + ni * 16 + fr) * 64 + fq * 16);
#pragma unroll
    for (int mi = 0; mi < 4; ++mi)
#pragma unroll
      for (int ni = 0; ni < 4; ++ni)
        acc[mi][ni] = __builtin_amdgcn_mfma_f32_16x16x32_f16(af[mi], bf[ni], acc[mi][ni], 0, 0, 0);
    __syncthreads();
  }

  // ---- epilogue: h = -acc/512 ; C/D layout: row=(lane>>4)*4+reg, col=lane&15 (m89)
  float* rowsmin = (float*)smem;             // [128][2]
  float* rowminC = (float*)(smem + 1024);    // [128]
  unsigned* msk = (unsigned*)(smem + 1536);  // [128][4]
  msk[tid] = 0;
  msk[tid + 256] = 0;
  const float sc = -0.001953125f;  // -2^-9
  float vr[4][4];
#pragma unroll
  for (int mi = 0; mi < 4; ++mi)
#pragma unroll
    for (int r = 0; r < 4; ++r) {
      float v = acc[mi][0][r] * sc;
      v = fminf(v, acc[mi][1][r] * sc);
      v = fminf(v, acc[mi][2][r] * sc);
      v = fminf(v, acc[mi][3][r] * sc);
#pragma unroll
      for (int off = 1; off < 16; off <<= 1) v = fminf(v, __shfl_xor(v, off, 64));
      vr[mi][r] = v;
      if (fr == 0) rowsmin[(wm * 64 + mi * 16 + fq * 4 + r) * 2 + wn] = v;
    }
  __syncthreads();
  if (tid < 128) {
    float rm = fminf(rowsmin[tid * 2], rowsmin[tid * 2 + 1]);
    rowminC[tid] = rm;
    lmin[(size_t)bn * NROW + bm * 128 + tid] = rm;  // [bn][row] coalesced
  }
  __syncthreads();
#pragma unroll
  for (int mi = 0; mi < 4; ++mi)
#pragma unroll
    for (int r = 0; r < 4; ++r) {
      const int row = wm * 64 + mi * 16 + fq * 4 + r;
      const float thr = rowminC[row] + MARGIN;
#pragma unroll
      for (int ni = 0; ni < 4; ++ni) {
        if (acc[mi][ni][r] * sc <= thr) {
          const int col = wn * 64 + ni * 16 + fr;
          atomicOr(&msk[row * 4 + (col >> 5)], 1u << (col & 31));
        }
      }
    }
  __syncthreads();
  if (tid < 128) masks[(size_t)bn * NROW + bm * 128 + tid] = *(const uint4*)&msk[tid * 4];
}

// Phase B: exact rescore of masked candidates; bit-identical to validated chain.
__global__ __launch_bounds__(256) void k_rescore(const float* __restrict__ z,
                                                 const float* __restrict__ e,
                                                 const float* __restrict__ es,
                                                 const float* __restrict__ lmin,
                                                 const uint4* __restrict__ masks,
                                                 int* __restrict__ out) {
  extern __shared__ float zl[];  // [k=256][mloc=64] 64KB
  const int t = threadIdx.x;
  const int rb = (int)blockIdx.x;
  const int bb = rb >> 4;
  const int hw0 = (rb & 15) << 6;
  const float* zbase = z + (size_t)bb * EDIM * 1024 + hw0;
#pragma unroll 4
  for (int rep = 0; rep < 64; ++rep) {
    int c = rep * 4 + (t >> 6);
    zl[c * 64 + (t & 63)] = zbase[(size_t)c * 1024 + (t & 63)];
  }
  __syncthreads();
  if (t < 64) {
    const int row = rb * 64 + t;
    // zs exactly as validated rounds: 4 x 64-k double-fma partials, paired sum
    double sq[4];
#pragma unroll
    for (int qt = 0; qt < 4; ++qt) {
      double s = 0.0;
      for (int k = qt * 64; k < qt * 64 + 64; ++k) {
        float v = zl[k * 64 + t];
        s = fma((double)v, (double)v, s);
      }
      sq[qt] = s;
    }
    const float zs = (float)((sq[0] + sq[1]) + (sq[2] + sq[3]));
    float gm = 3.402823466e+38f;
    for (int bn = 0; bn < NBN; ++bn) gm = fminf(gm, lmin[(size_t)bn * NROW + row]);
    const float thr = gm + MARGIN;
    float bestd = 3.402823466e+38f;
    int besti = 0;
#pragma unroll 1
    for (int bn = 0; bn < NBN; ++bn) {
      if (lmin[(size_t)bn * NROW + row] <= thr) {
        uint4 mk = masks[(size_t)bn * NROW + row];
        unsigned w[4] = {mk.x, mk.y, mk.z, mk.w};
#pragma unroll 1
        for (int q = 0; q < 4; ++q) {
          unsigned u = w[q];
          while (u) {
            int b = __ffs(u) - 1;
            u &= u - 1;
            const int code = bn * 128 + q * 32 + b;
            const float* ep = e + (size_t)code * EDIM;
            float dot = 0.0f;
            for (int k = 0; k < EDIM; k += 4) {  // ascending k, sequential fp32 chain
              float4 ev = *(const float4*)(ep + k);
              dot = fmaf(zl[(k + 0) * 64 + t], ev.x, dot);
              dot = fmaf(zl[(k + 1) * 64 + t], ev.y, dot);
              dot = fmaf(zl[(k + 2) * 64 + t], ev.z, dot);
              dot = fmaf(zl[(k + 3) * 64 + t], ev.w, dot);
            }
            float d = (zs + es[code]) - 2.0f * dot;
            if (d < bestd) {  // strict <, ascending code order -> lowest index wins
              bestd = d;
              besti = code;
            }
          }
        }
      }
    }
    out[row] = besti;
  }
}

// ================= fallback (round-1 verbatim, passed at 1654us) =================
__global__ __launch_bounds__(256) void k_merge(const float* __restrict__ candv,
                                               const int* __restrict__ candi,
                                               int* __restrict__ out) {
  int n = blockIdx.x * 256 + threadIdx.x;
  float v0 = candv[n], v1 = candv[NROW + n];
  int i0 = candi[n], i1 = candi[NROW + n];
  out[n] = (v1 < v0) ? i1 : i0;
}

template <int SPLIT>
__global__ __launch_bounds__(256, 2) void k_main_fb(const float* __restrict__ z,
                                                    const float* __restrict__ e,
                                                    const float* __restrict__ es,
                                                    float* __restrict__ candv,
                                                    int* __restrict__ candi,
                                                    int* __restrict__ outd) {
  extern __shared__ char smem[];
  float* As = (float*)smem;
  float* Bs = (float*)(smem + 16384);
  double* zred = (double*)(smem + 16384 + 32768);
  float* zsf = (float*)(smem + 16384 + 32768 + 2048);
  const int tid = threadIdx.x;
  const int lane = tid & 63;
  const int wv = tid >> 6;
  const int tm = tid & 7;
  const int tn = tid >> 3;
  const int rt = (int)blockIdx.x / SPLIT;
  const int sp = (int)blockIdx.x % SPLIT;
  const int bb = rt >> 4;
  const int hw0 = (rt & 15) << 6;
  const float* zb = z + bb * (EDIM * 1024) + hw0;
  const int codeBase = sp * (NCODE / SPLIT);
  const int NSTEP = (NCODE / SPLIT) / 256 * 8;
  auto stageA = [&](int buf, int gts) {
    const int k0 = (gts & 7) * 32;
    const float* g0 = zb + (size_t)k0 * 1024 + lane;
    float* l0 = As + buf * 2048 + (wv * 8) * 64;
#pragma unroll
    for (int s = 0; s < 8; ++s) gll4(g0 + (size_t)(wv * 8 + s) * 1024, l0 + s * 64);
  };
  float4 bpre[8];
  auto loadB = [&](int gts) {
    const int ct = gts >> 3, k0 = (gts & 7) * 32;
    const float* g = e + (size_t)(codeBase + ct * 256 + tid) * 256 + k0;
#pragma unroll
    for (int s = 0; s < 8; ++s) bpre[s] = *(const float4*)(g + s * 4);
  };
  auto writeB = [&](int buf) {
    float* bw_ = Bs + buf * 8192 + tid;
#pragma unroll
    for (int s = 0; s < 8; ++s) {
      bw_[(4 * s + 0) * 256] = bpre[s].x;
      bw_[(4 * s + 1) * 256] = bpre[s].y;
      bw_[(4 * s + 2) * 256] = bpre[s].z;
      bw_[(4 * s + 3) * 256] = bpre[s].w;
    }
  };
  stageA(0, 0);
  loadB(0);
  {
    const int m = tid & 63, qt = tid >> 6;
    const float* zp = zb + (size_t)(qt * 64) * 1024 + m;
    double s = 0.0;
    for (int k = 0; k < 64; ++k) {
      float v = zp[(size_t)k * 1024];
      s = fma((double)v, (double)v, s);
    }
    zred[qt * 64 + m] = s;
  }
  writeB(0);
  __syncthreads();
  if (tid < 64) {
    double sz = (zred[tid] + zred[64 + tid]) + (zred[128 + tid] + zred[192 + tid]);
    zsf[tid] = (float)sz;
  }
  __syncthreads();
  float zsr[8];
#pragma unroll
  for (int i = 0; i < 8; ++i) zsr[i] = zsf[tm * 8 + i];
  __syncthreads();
  float bestv[8];
  int besti[8];
#pragma unroll
  for (int i = 0; i < 8; ++i) {
    bestv[i] = 3.402823466e+38f;
    besti[i] = 0;
  }
  float acc[8][8];
  int cur = 0;
#pragma unroll 1
  for (int step = 0; step < NSTEP; ++step) {
    const int kc = step & 7, ct = step >> 3;
    if (step + 1 < NSTEP) {
      stageA(cur ^ 1, step + 1);
      loadB(step + 1);
    }
    if (kc == 0) {
#pragma unroll
      for (int i = 0; i < 8; ++i)
#pragma unroll
        for (int j = 0; j < 8; ++j) acc[i][j] = 0.0f;
    }
    const float* ak = As + cur * 2048 + tm * 8;
    const float* bk = Bs + cur * 8192 + tn * 8;
#pragma unroll 4
    for (int k = 0; k < 32; ++k) {
      float4 a0 = *(const float4*)(ak + k * 64);
      float4 a1 = *(const float4*)(ak + k * 64 + 4);
      float4 b0 = *(const float4*)(bk + k * 256);
      float4 b1 = *(const float4*)(bk + k * 256 + 4);
      float av[8] = {a0.x, a0.y, a0.z, a0.w, a1.x, a1.y, a1.z, a1.w};
      float bw[8] = {b0.x, b0.y, b0.z, b0.w, b1.x, b1.y, b1.z, b1.w};
#pragma unroll
      for (int i = 0; i < 8; ++i)
#pragma unroll
        for (int j = 0; j < 8; ++j) acc[i][j] = fmaf(av[i], bw[j], acc[i][j]);
    }
    if (step + 1 < NSTEP) writeB(cur ^ 1);
    if (kc == 7) {
      const int cb = codeBase + ct * 256 + tn * 8;
#pragma unroll
      for (int j = 0; j < 8; ++j) {
        float ej = es[cb + j];
#pragma unroll
        for (int i = 0; i < 8; ++i) {
          float d = (zsr[i] + ej) - 2.0f * acc[i][j];
          if (d < bestv[i]) {
            bestv[i] = d;
            besti[i] = cb + j;
          }
        }
      }
    }
    __syncthreads();
    cur ^= 1;
  }
  float* Lv = (float*)(smem + 16384);
  int* Li = (int*)(smem + 16384 + 8192);
#pragma unroll
  for (int i = 0; i < 8; ++i) {
    Lv[(tm * 8 + i) * 32 + tn] = bestv[i];
    Li[(tm * 8 + i) * 32 + tn] = besti[i];
  }
  __syncthreads();
  if (tid < 64) {
    float bv = Lv[tid * 32];
    int bi = Li[tid * 32];
#pragma unroll 1
    for (int g2 = 1; g2 < 32; ++g2) {
      float v = Lv[tid * 32 + g2];
      int ii = Li[tid * 32 + g2];
      if (v < bv || (v == bv && ii < bi)) {
        bv = v;
        bi = ii;
      }
    }
    if (SPLIT == 1) outd[rt * 64 + tid] = bi;
    else {
      candv[sp * NROW + rt * 64 + tid] = bv;
      candi[sp * NROW + rt * 64 + tid] = bi;
    }
  }
}

extern "C" void kernel_launch(void* const* d_in, const int* in_sizes, int n_in,
                              void* d_out, int out_size, void* d_ws, size_t ws_size,
                              hipStream_t stream) {
  const float* z = (const float*)d_in[0];
  const float* e = (const float*)d_in[1];
  int* out = (int*)d_out;

  char* ws = (char*)d_ws;
  float* es = (float*)ws;                                   // 64KB
  const size_t off_zh = 65536;                              // 8MB
  const size_t off_eh = off_zh + (size_t)NROW * EDIM * 2;   // 8MB
  const size_t off_lmin = off_eh + (size_t)NCODE * EDIM * 2;          // 8MB
  const size_t off_masks = off_lmin + (size_t)NROW * NBN * 4;         // 32MB
  const size_t need = off_masks + (size_t)NROW * NBN * 16;

  k_es<<<dim3(NCODE / 4), dim3(256), 0, stream>>>(e, es);

  if (ws_size >= need) {
    _Float16* Zh = (_Float16*)(ws + off_zh);
    _Float16* Eh = (_Float16*)(ws + off_eh);
    float* lmin = (float*)(ws + off_lmin);
    uint4* masks = (uint4*)(ws + off_masks);
    k_cvt_e<<<dim3(NCODE), dim3(256), 0, stream>>>(e, Eh);
    k_cvt_z<<<dim3(256), dim3(256), 0, stream>>>(z, Zh);
    k_gemm<<<dim3(16384), dim3(256), 0, stream>>>(Zh, Eh, lmin, masks);
    hipFuncSetAttribute(reinterpret_cast<const void*>(&k_rescore),
                        hipFuncAttributeMaxDynamicSharedMemorySize, 65536);
    k_rescore<<<dim3(256), dim3(256), 65536, stream>>>(z, e, es, lmin, masks, out);
  } else {
    float* candv = (float*)(ws + 65536);
    int* candi = (int*)(ws + 65536 + 131072);
    const size_t smem = 16384 + 65536;
    if (ws_size >= 65536 + 131072 + 131072) {
      hipFuncSetAttribute(reinterpret_cast<const void*>(&k_main_fb<2>),
                          hipFuncAttributeMaxDynamicSharedMemorySize, (int)smem);
      k_main_fb<2><<<dim3(512), dim3(256), smem, stream>>>(z, e, es, candv, candi, out);
      k_merge<<<dim3(NROW / 256), dim3(256), 0, stream>>>(candv, candi, out);
    } else {
      hipFuncSetAttribute(reinterpret_cast<const void*>(&k_main_fb<1>),
                          hipFuncAttributeMaxDynamicSharedMemorySize, (int)smem);
      k_main_fb<1><<<dim3(256), dim3(256), smem, stream>>>(z, e, es, candv, candi, out);
    }
  }
}

// Round 5
// 417.616 us; speedup vs baseline: 5.4607x; 1.6638x over previous
//
#include <hip/hip_runtime.h>

#define EDIM 256
#define NROW 16384
#define NCODE 16384
#define NBN 128
#define MARGIN 2.0e-4f

typedef _Float16 f16x8 __attribute__((ext_vector_type(8)));
typedef float f32x4 __attribute__((ext_vector_type(4)));

__device__ __forceinline__ void gll16(const void* g, void* l) {
  __builtin_amdgcn_global_load_lds((const __attribute__((address_space(1))) void*)g,
                                   (__attribute__((address_space(3))) void*)l, 16, 0, 0);
}
__device__ __forceinline__ void gll4(const void* g, void* l) {
  __builtin_amdgcn_global_load_lds((const __attribute__((address_space(1))) void*)g,
                                   (__attribute__((address_space(3))) void*)l, 4, 0, 0);
}

// ||e_j||^2 in double, rounded once to f32 (identical to validated rounds)
__global__ __launch_bounds__(256) void k_es(const float* __restrict__ e,
                                            float* __restrict__ es) {
  const int row = blockIdx.x * 4 + (threadIdx.x >> 6);
  const int lane = threadIdx.x & 63;
  float4 v = *(const float4*)&e[row * EDIM + lane * 4];
  double s = (double)v.x * v.x + (double)v.y * v.y + (double)v.z * v.z + (double)v.w * v.w;
#pragma unroll
  for (int off = 32; off > 0; off >>= 1) s += __shfl_down(s, off, 64);
  if (lane == 0) es[row] = (float)s;
}

// e [n][k] f32 -> Eh [n][k] f16, scaled by 2^10 (exact pow2)
__global__ __launch_bounds__(256) void k_cvt_e(const float* __restrict__ e,
                                               _Float16* __restrict__ Eh) {
  const int n = blockIdx.x;
  Eh[n * EDIM + threadIdx.x] = (_Float16)(e[n * EDIM + threadIdx.x] * 1024.0f);
}

// z [16][256][32][32] f32 -> Zh [m=16384][k=256] f16 (transpose c<->hw via LDS)
__global__ __launch_bounds__(256) void k_cvt_z(const float* __restrict__ z,
                                               _Float16* __restrict__ Zh) {
  __shared__ float zl[EDIM * 64];  // [c][mloc] 64KB
  const int t = threadIdx.x;
  const int rb = blockIdx.x;
  const int bb = rb >> 4;
  const int hw0 = (rb & 15) << 6;
  const float* zbase = z + (size_t)bb * EDIM * 1024 + hw0;
#pragma unroll 4
  for (int rep = 0; rep < 64; ++rep) {
    int c = rep * 4 + (t >> 6);
    zl[c * 64 + (t & 63)] = zbase[(size_t)c * 1024 + (t & 63)];
  }
  __syncthreads();
  const int mloc = t >> 2, part = t & 3;
#pragma unroll
  for (int i = 0; i < 8; ++i) {
    int c0 = part * 64 + i * 8;
    f16x8 v;
#pragma unroll
    for (int j = 0; j < 8; ++j) v[j] = (_Float16)zl[(c0 + j) * 64 + mloc];
    *(f16x8*)&Zh[(size_t)(rb * 64 + mloc) * EDIM + c0] = v;
  }
}

// Phase A: f16 MFMA GEMM h = -2*(z.e). Per (row, 128-code block): local min +
// 128-bit mask of codes within MARGIN of local min. (unchanged from round 4)
__global__ __launch_bounds__(256, 2) void k_gemm(const _Float16* __restrict__ Zh,
                                                 const _Float16* __restrict__ Eh,
                                                 float* __restrict__ lmin,
                                                 uint4* __restrict__ masks) {
  __shared__ __align__(16) char smem[32768];

  const int tid = threadIdx.x;
  const int lane = tid & 63;
  const int wv = tid >> 6;
  const int wm = wv & 1, wn = wv >> 1;
  const int fr = lane & 15;
  const int fq = lane >> 4;

  const int bid = (int)blockIdx.x;
  const int wgid = (bid & 7) * 2048 + (bid >> 3);
  const int st = wgid >> 8, wi = wgid & 255;
  const int bm = ((st & 7) << 4) | (wi & 15);
  const int bn = ((st >> 3) << 4) | (wi >> 4);

  const char* zh_b = (const char*)Zh;
  const char* eh_b = (const char*)Eh;

  auto stage = [&](int buf, int s) {
#pragma unroll
    for (int i = 0; i < 2; ++i) {
      const int L = (i * 256 + tid) * 16;
      const int row = L >> 6, kb = L & 63;
      gll16(zh_b + (size_t)(bm * 128 + row) * 512 + s * 64 + kb,
            smem + buf * 8192 + L);
      gll16(eh_b + (size_t)(bn * 128 + row) * 512 + s * 64 + kb,
            smem + 16384 + buf * 8192 + L);
    }
  };

  f32x4 acc[4][4];
#pragma unroll
  for (int i = 0; i < 4; ++i)
#pragma unroll
    for (int j = 0; j < 4; ++j) acc[i][j] = (f32x4)0.0f;

  stage(0, 0);
  __syncthreads();
#pragma unroll 1
  for (int s = 0; s < 8; ++s) {
    if (s + 1 < 8) stage((s + 1) & 1, s + 1);
    const char* aB = smem + (s & 1) * 8192;
    const char* bB = smem + 16384 + (s & 1) * 8192;
    f16x8 af[4], bf[4];
#pragma unroll
    for (int mi = 0; mi < 4; ++mi)
      af[mi] = *(const f16x8*)(aB + (wm * 64 + mi * 16 + fr) * 64 + fq * 16);
#pragma unroll
    for (int ni = 0; ni < 4; ++ni)
      bf[ni] = *(const f16x8*)(bB + (wn * 64 + ni * 16 + fr) * 64 + fq * 16);
#pragma unroll
    for (int mi = 0; mi < 4; ++mi)
#pragma unroll
      for (int ni = 0; ni < 4; ++ni)
        acc[mi][ni] = __builtin_amdgcn_mfma_f32_16x16x32_f16(af[mi], bf[ni], acc[mi][ni], 0, 0, 0);
    __syncthreads();
  }

  float* rowsmin = (float*)smem;
  float* rowminC = (float*)(smem + 1024);
  unsigned* msk = (unsigned*)(smem + 1536);
  msk[tid] = 0;
  msk[tid + 256] = 0;
  const float sc = -0.001953125f;  // -2^-9
#pragma unroll
  for (int mi = 0; mi < 4; ++mi)
#pragma unroll
    for (int r = 0; r < 4; ++r) {
      float v = acc[mi][0][r] * sc;
      v = fminf(v, acc[mi][1][r] * sc);
      v = fminf(v, acc[mi][2][r] * sc);
      v = fminf(v, acc[mi][3][r] * sc);
#pragma unroll
      for (int off = 1; off < 16; off <<= 1) v = fminf(v, __shfl_xor(v, off, 64));
      if (fr == 0) rowsmin[(wm * 64 + mi * 16 + fq * 4 + r) * 2 + wn] = v;
    }
  __syncthreads();
  if (tid < 128) {
    float rm = fminf(rowsmin[tid * 2], rowsmin[tid * 2 + 1]);
    rowminC[tid] = rm;
    lmin[(size_t)bn * NROW + bm * 128 + tid] = rm;
  }
  __syncthreads();
#pragma unroll
  for (int mi = 0; mi < 4; ++mi)
#pragma unroll
    for (int r = 0; r < 4; ++r) {
      const int row = wm * 64 + mi * 16 + fq * 4 + r;
      const float thr = rowminC[row] + MARGIN;
#pragma unroll
      for (int ni = 0; ni < 4; ++ni) {
        if (acc[mi][ni][r] * sc <= thr) {
          const int col = wn * 64 + ni * 16 + fr;
          atomicOr(&msk[row * 4 + (col >> 5)], 1u << (col & 31));
        }
      }
    }
  __syncthreads();
  if (tid < 128) masks[(size_t)bn * NROW + bm * 128 + tid] = *(const uint4*)&msk[tid * 4];
}

// Phase B: exact rescore. All 256 threads active: thread = (row r=t>>2, quarter q=t&3).
// lmin staged to LDS (coalesced); zs quarters + shuffle combine reproduce the
// validated double-sum bit-exactly; lexicographic (d,idx) combine keeps tie rule.
__global__ __launch_bounds__(256) void k_rescore(const float* __restrict__ z,
                                                 const float* __restrict__ e,
                                                 const float* __restrict__ es,
                                                 const float* __restrict__ lmin,
                                                 const uint4* __restrict__ masks,
                                                 int* __restrict__ out) {
  extern __shared__ float zl[];        // [256][64] 64KB
  float* lmin_s = zl + EDIM * 64;      // [128][64] 32KB
  const int t = threadIdx.x;
  const int rb = (int)blockIdx.x;
  const int bb = rb >> 4;
  const int hw0 = (rb & 15) << 6;
  const int r0 = rb * 64;
  const float* zbase = z + (size_t)bb * EDIM * 1024 + hw0;
#pragma unroll 4
  for (int rep = 0; rep < 64; ++rep) {
    int c = rep * 4 + (t >> 6);
    zl[c * 64 + (t & 63)] = zbase[(size_t)c * 1024 + (t & 63)];
  }
#pragma unroll 4
  for (int i = 0; i < 32; ++i) {
    int bn = i * 4 + (t >> 6);
    lmin_s[bn * 64 + (t & 63)] = lmin[(size_t)bn * NROW + r0 + (t & 63)];
  }
  __syncthreads();

  const int r = t >> 2, q = t & 3;
  const int row = r0 + r;

  // zs quarter q: double fma chain over c in [q*64, q*64+64) — validated order
  double sq = 0.0;
  {
    const float* zq = zl + (q * 64) * 64 + r;
    for (int k = 0; k < 64; ++k) {
      float v = zq[k * 64];
      sq = fma((double)v, (double)v, sq);
    }
  }
  double s01 = sq + __shfl_xor(sq, 1, 64);        // lanes {q0,q1}/{q2,q3} pair-sums
  double zsd = s01 + __shfl_xor(s01, 2, 64);      // (sq0+sq1)+(sq2+sq3) exactly
  const float zs = (float)zsd;

  // gm = exact min over all 128 bn (order-free)
  float g = 3.402823466e+38f;
#pragma unroll 8
  for (int j = 0; j < 32; ++j) g = fminf(g, lmin_s[(q * 32 + j) * 64 + r]);
  g = fminf(g, __shfl_xor(g, 1, 64));
  g = fminf(g, __shfl_xor(g, 2, 64));
  const float thr = g + MARGIN;

  float bestd = 3.402823466e+38f;
  int besti = 0x7fffffff;
#pragma unroll 1
  for (int j = 0; j < 32; ++j) {
    const int bn = q * 32 + j;
    if (lmin_s[bn * 64 + r] <= thr) {
      uint4 mk = masks[(size_t)bn * NROW + row];
      unsigned w[4] = {mk.x, mk.y, mk.z, mk.w};
#pragma unroll 1
      for (int qq = 0; qq < 4; ++qq) {
        unsigned u = w[qq];
        while (u) {
          int b = __ffs(u) - 1;
          u &= u - 1;
          const int code = bn * 128 + qq * 32 + b;
          const float* ep = e + (size_t)code * EDIM;
          float dot = 0.0f;
          for (int k = 0; k < EDIM; k += 4) {  // ascending k, sequential fp32 chain
            float4 ev = *(const float4*)(ep + k);
            dot = fmaf(zl[(k + 0) * 64 + r], ev.x, dot);
            dot = fmaf(zl[(k + 1) * 64 + r], ev.y, dot);
            dot = fmaf(zl[(k + 2) * 64 + r], ev.z, dot);
            dot = fmaf(zl[(k + 3) * 64 + r], ev.w, dot);
          }
          float d = (zs + es[code]) - 2.0f * dot;
          if (d < bestd) {  // strict <, ascending code order within thread
            bestd = d;
            besti = code;
          }
        }
      }
    }
  }
  // lexicographic (d, idx) combine across the 4 quarter-lanes
#pragma unroll
  for (int off = 1; off <= 2; off <<= 1) {
    float ov = __shfl_xor(bestd, off, 64);
    int oi = __shfl_xor(besti, off, 64);
    if (ov < bestd || (ov == bestd && oi < besti)) {
      bestd = ov;
      besti = oi;
    }
  }
  if (q == 0) out[row] = besti;
}

// ================= fallback (round-1 verbatim, passed at 1654us) =================
__global__ __launch_bounds__(256) void k_merge(const float* __restrict__ candv,
                                               const int* __restrict__ candi,
                                               int* __restrict__ out) {
  int n = blockIdx.x * 256 + threadIdx.x;
  float v0 = candv[n], v1 = candv[NROW + n];
  int i0 = candi[n], i1 = candi[NROW + n];
  out[n] = (v1 < v0) ? i1 : i0;
}

template <int SPLIT>
__global__ __launch_bounds__(256, 2) void k_main_fb(const float* __restrict__ z,
                                                    const float* __restrict__ e,
                                                    const float* __restrict__ es,
                                                    float* __restrict__ candv,
                                                    int* __restrict__ candi,
                                                    int* __restrict__ outd) {
  extern __shared__ char smemc[];
  float* As = (float*)smemc;
  float* Bs = (float*)(smemc + 16384);
  double* zred = (double*)(smemc + 16384 + 32768);
  float* zsf = (float*)(smemc + 16384 + 32768 + 2048);
  const int tid = threadIdx.x;
  const int lane = tid & 63;
  const int wv = tid >> 6;
  const int tm = tid & 7;
  const int tn = tid >> 3;
  const int rt = (int)blockIdx.x / SPLIT;
  const int sp = (int)blockIdx.x % SPLIT;
  const int bb = rt >> 4;
  const int hw0 = (rt & 15) << 6;
  const float* zb = z + bb * (EDIM * 1024) + hw0;
  const int codeBase = sp * (NCODE / SPLIT);
  const int NSTEP = (NCODE / SPLIT) / 256 * 8;
  auto stageA = [&](int buf, int gts) {
    const int k0 = (gts & 7) * 32;
    const float* g0 = zb + (size_t)k0 * 1024 + lane;
    float* l0 = As + buf * 2048 + (wv * 8) * 64;
#pragma unroll
    for (int s = 0; s < 8; ++s) gll4(g0 + (size_t)(wv * 8 + s) * 1024, l0 + s * 64);
  };
  float4 bpre[8];
  auto loadB = [&](int gts) {
    const int ct = gts >> 3, k0 = (gts & 7) * 32;
    const float* g = e + (size_t)(codeBase + ct * 256 + tid) * 256 + k0;
#pragma unroll
    for (int s = 0; s < 8; ++s) bpre[s] = *(const float4*)(g + s * 4);
  };
  auto writeB = [&](int buf) {
    float* bw_ = Bs + buf * 8192 + tid;
#pragma unroll
    for (int s = 0; s < 8; ++s) {
      bw_[(4 * s + 0) * 256] = bpre[s].x;
      bw_[(4 * s + 1) * 256] = bpre[s].y;
      bw_[(4 * s + 2) * 256] = bpre[s].z;
      bw_[(4 * s + 3) * 256] = bpre[s].w;
    }
  };
  stageA(0, 0);
  loadB(0);
  {
    const int m = tid & 63, qt = tid >> 6;
    const float* zp = zb + (size_t)(qt * 64) * 1024 + m;
    double s = 0.0;
    for (int k = 0; k < 64; ++k) {
      float v = zp[(size_t)k * 1024];
      s = fma((double)v, (double)v, s);
    }
    zred[qt * 64 + m] = s;
  }
  writeB(0);
  __syncthreads();
  if (tid < 64) {
    double sz = (zred[tid] + zred[64 + tid]) + (zred[128 + tid] + zred[192 + tid]);
    zsf[tid] = (float)sz;
  }
  __syncthreads();
  float zsr[8];
#pragma unroll
  for (int i = 0; i < 8; ++i) zsr[i] = zsf[tm * 8 + i];
  __syncthreads();
  float bestv[8];
  int besti[8];
#pragma unroll
  for (int i = 0; i < 8; ++i) {
    bestv[i] = 3.402823466e+38f;
    besti[i] = 0;
  }
  float acc[8][8];
  int cur = 0;
#pragma unroll 1
  for (int step = 0; step < NSTEP; ++step) {
    const int kc = step & 7, ct = step >> 3;
    if (step + 1 < NSTEP) {
      stageA(cur ^ 1, step + 1);
      loadB(step + 1);
    }
    if (kc == 0) {
#pragma unroll
      for (int i = 0; i < 8; ++i)
#pragma unroll
        for (int j = 0; j < 8; ++j) acc[i][j] = 0.0f;
    }
    const float* ak = As + cur * 2048 + tm * 8;
    const float* bk = Bs + cur * 8192 + tn * 8;
#pragma unroll 4
    for (int k = 0; k < 32; ++k) {
      float4 a0 = *(const float4*)(ak + k * 64);
      float4 a1 = *(const float4*)(ak + k * 64 + 4);
      float4 b0 = *(const float4*)(bk + k * 256);
      float4 b1 = *(const float4*)(bk + k * 256 + 4);
      float av[8] = {a0.x, a0.y, a0.z, a0.w, a1.x, a1.y, a1.z, a1.w};
      float bw[8] = {b0.x, b0.y, b0.z, b0.w, b1.x, b1.y, b1.z, b1.w};
#pragma unroll
      for (int i = 0; i < 8; ++i)
#pragma unroll
        for (int j = 0; j < 8; ++j) acc[i][j] = fmaf(av[i], bw[j], acc[i][j]);
    }
    if (step + 1 < NSTEP) writeB(cur ^ 1);
    if (kc == 7) {
      const int cb = codeBase + ct * 256 + tn * 8;
#pragma unroll
      for (int j = 0; j < 8; ++j) {
        float ej = es[cb + j];
#pragma unroll
        for (int i = 0; i < 8; ++i) {
          float d = (zsr[i] + ej) - 2.0f * acc[i][j];
          if (d < bestv[i]) {
            bestv[i] = d;
            besti[i] = cb + j;
          }
        }
      }
    }
    __syncthreads();
    cur ^= 1;
  }
  float* Lv = (float*)(smemc + 16384);
  int* Li = (int*)(smemc + 16384 + 8192);
#pragma unroll
  for (int i = 0; i < 8; ++i) {
    Lv[(tm * 8 + i) * 32 + tn] = bestv[i];
    Li[(tm * 8 + i) * 32 + tn] = besti[i];
  }
  __syncthreads();
  if (tid < 64) {
    float bv = Lv[tid * 32];
    int bi = Li[tid * 32];
#pragma unroll 1
    for (int g2 = 1; g2 < 32; ++g2) {
      float v = Lv[tid * 32 + g2];
      int ii = Li[tid * 32 + g2];
      if (v < bv || (v == bv && ii < bi)) {
        bv = v;
        bi = ii;
      }
    }
    if (SPLIT == 1) outd[rt * 64 + tid] = bi;
    else {
      candv[sp * NROW + rt * 64 + tid] = bv;
      candi[sp * NROW + rt * 64 + tid] = bi;
    }
  }
}

extern "C" void kernel_launch(void* const* d_in, const int* in_sizes, int n_in,
                              void* d_out, int out_size, void* d_ws, size_t ws_size,
                              hipStream_t stream) {
  const float* z = (const float*)d_in[0];
  const float* e = (const float*)d_in[1];
  int* out = (int*)d_out;

  char* ws = (char*)d_ws;
  float* es = (float*)ws;
  const size_t off_zh = 65536;
  const size_t off_eh = off_zh + (size_t)NROW * EDIM * 2;
  const size_t off_lmin = off_eh + (size_t)NCODE * EDIM * 2;
  const size_t off_masks = off_lmin + (size_t)NROW * NBN * 4;
  const size_t need = off_masks + (size_t)NROW * NBN * 16;

  k_es<<<dim3(NCODE / 4), dim3(256), 0, stream>>>(e, es);

  if (ws_size >= need) {
    _Float16* Zh = (_Float16*)(ws + off_zh);
    _Float16* Eh = (_Float16*)(ws + off_eh);
    float* lmin = (float*)(ws + off_lmin);
    uint4* masks = (uint4*)(ws + off_masks);
    k_cvt_e<<<dim3(NCODE), dim3(256), 0, stream>>>(e, Eh);
    k_cvt_z<<<dim3(256), dim3(256), 0, stream>>>(z, Zh);
    k_gemm<<<dim3(16384), dim3(256), 0, stream>>>(Zh, Eh, lmin, masks);
    hipFuncSetAttribute(reinterpret_cast<const void*>(&k_rescore),
                        hipFuncAttributeMaxDynamicSharedMemorySize, 98304);
    k_rescore<<<dim3(256), dim3(256), 98304, stream>>>(z, e, es, lmin, masks, out);
  } else {
    float* candv = (float*)(ws + 65536);
    int* candi = (int*)(ws + 65536 + 131072);
    const size_t smem = 16384 + 65536;
    if (ws_size >= 65536 + 131072 + 131072) {
      hipFuncSetAttribute(reinterpret_cast<const void*>(&k_main_fb<2>),
                          hipFuncAttributeMaxDynamicSharedMemorySize, (int)smem);
      k_main_fb<2><<<dim3(512), dim3(256), smem, stream>>>(z, e, es, candv, candi, out);
      k_merge<<<dim3(NROW / 256), dim3(256), 0, stream>>>(candv, candi, out);
    } else {
      hipFuncSetAttribute(reinterpret_cast<const void*>(&k_main_fb<1>),
                          hipFuncAttributeMaxDynamicSharedMemorySize, (int)smem);
      k_main_fb<1><<<dim3(256), dim3(256), smem, stream>>>(z, e, es, candv, candi, out);
    }
  }
}